// Round 3
// baseline (28399.417 us; speedup 1.0000x reference)
//
#include <hip/hip_runtime.h>
#include <stdint.h>

#define HID 1024
#define NGATE 4096
#define BATCH 256
#define TENC 128
#define VOCAB 1024
#define NOUT 125
#define TDEC (16 + NOUT)   // 141
#define MAXTHINK 16
#define STOPCLS 1023

// RNG variant: 0 = original split-half (jax_threefry_partitionable=False)
//              1 = partitionable-parity guess (WRONG - that's split's layout)
//              2 = partitionable, counter=i, take o0 (WRONG)
//              3 = partitionable, counter=(0,i), bits = o0 ^ o1   (jax/_src/prng.py)
#define RNGV 3

// ---------------- threefry2x32 (exact JAX semantics) ----------------
__device__ __forceinline__ uint32_t rotl32(uint32_t v, int r){ return (v<<r)|(v>>(32-r)); }

__device__ __forceinline__ void tf2x32(uint32_t k0, uint32_t k1, uint32_t x0, uint32_t x1,
                                       uint32_t& o0, uint32_t& o1)
{
  uint32_t k2 = k0 ^ k1 ^ 0x1BD11BDAu;
  x0 += k0; x1 += k1;
#define R4(a,b,cc,d) x0+=x1;x1=rotl32(x1,a);x1^=x0; x0+=x1;x1=rotl32(x1,b);x1^=x0; \
                     x0+=x1;x1=rotl32(x1,cc);x1^=x0; x0+=x1;x1=rotl32(x1,d);x1^=x0;
  R4(13,15,26,6)  x0+=k1; x1+=k2+1u;
  R4(17,29,16,24) x0+=k2; x1+=k0+2u;
  R4(13,15,26,6)  x0+=k0; x1+=k1+3u;
  R4(17,29,16,24) x0+=k1; x1+=k2+4u;
  R4(13,15,26,6)  x0+=k2; x1+=k0+5u;
#undef R4
  o0 = x0; o1 = x1;
}

// random bits for flat element i of a (256,1024) f32 draw under folded key (fk0,fk1)
__device__ __forceinline__ uint32_t jax_bits(uint32_t fk0, uint32_t fk1, uint32_t i)
{
  uint32_t o0, o1;
#if RNGV == 0
  bool lo = (i < 131072u);
  uint32_t x0 = lo ? i : (i - 131072u);
  uint32_t x1 = lo ? (i + 131072u) : i;
  tf2x32(fk0, fk1, x0, x1, o0, o1);
  return lo ? o0 : o1;
#elif RNGV == 1
  tf2x32(fk0, fk1, 0u, i >> 1, o0, o1);
  return (i & 1u) ? o1 : o0;
#elif RNGV == 2
  tf2x32(fk0, fk1, 0u, i, o0, o1);
  return o0;
#else
  tf2x32(fk0, fk1, 0u, i, o0, o1);   // 64-bit iota: hi=0, lo=i
  return o0 ^ o1;                     // XOR-fold of the two PRF words
#endif
}

// XLA lowers jax.nn.sigmoid (logistic) via tanh; f32-faithful either way
__device__ __forceinline__ float sigm(float x){ return 0.5f + 0.5f*tanhf(0.5f*x); }

// ---------------- prep: bias sum, zero h/c, gather dec_in, init state ----------------
__global__ __launch_bounds__(256) void prep_kernel(
    const float* __restrict__ b_ih, const float* __restrict__ b_hh,
    const float* __restrict__ x, const int* __restrict__ lengths,
    float* __restrict__ bsum, float* __restrict__ h, float* __restrict__ c,
    float* __restrict__ cur, int* __restrict__ is_think0,
    int* __restrict__ think_steps, int* __restrict__ out_steps)
{
  int idx = blockIdx.x*256 + threadIdx.x;           // 0 .. 262143
  if (idx < NGATE) bsum[idx] = b_ih[idx] + b_hh[idx];
  if (idx < BATCH){ is_think0[idx] = 1; think_steps[idx] = 0; out_steps[idx] = 0; }
  h[idx] = 0.f; c[idx] = 0.f;
  int b = idx >> 10, k = idx & (HID-1);
  int L = lengths[b];
  cur[idx] = x[((size_t)b*TENC + (size_t)(L-1))*HID + k];
}

// ---------------- tiled f32 GEMM: C[b][j] = sum_k A[b][k] * W[j][k] ----------------
#define GBM 64
#define GBN 64
#define GBK 16

__global__ __launch_bounds__(256) void gemm_nt(
    const float* __restrict__ A1, int lda1,
    const float* __restrict__ A2,
    const float* __restrict__ W1, const float* __restrict__ W2,
    float* __restrict__ C0, float* __restrict__ C1, int N)
{
  int z = blockIdx.z;
  const float* A = z ? A2 : A1;
  const float* W = z ? W2 : W1;
  int lda = z ? HID : lda1;
  float* C = z ? C1 : C0;

  __shared__ float As[GBK][GBM];
  __shared__ float Bs[GBK][GBN];
  int tid = threadIdx.x;
  int j0 = blockIdx.x * GBN;
  int b0 = blockIdx.y * GBM;
  int li = tid >> 2;            // 0..63: row within tile for loading
  int lk = (tid & 3) << 2;      // 0,4,8,12: k offset for float4 load
  int tm = tid >> 4, tn = tid & 15;
  float acc[4][4] = {};

  for (int k0 = 0; k0 < HID; k0 += GBK){
    float4 av = *(const float4*)(A + (size_t)(b0+li)*lda + k0 + lk);
    float4 wv = *(const float4*)(W + (size_t)(j0+li)*HID + k0 + lk);
    __syncthreads();
    As[lk+0][li]=av.x; As[lk+1][li]=av.y; As[lk+2][li]=av.z; As[lk+3][li]=av.w;
    Bs[lk+0][li]=wv.x; Bs[lk+1][li]=wv.y; Bs[lk+2][li]=wv.z; Bs[lk+3][li]=wv.w;
    __syncthreads();
    #pragma unroll
    for (int k=0;k<GBK;k++){
      float4 a4 = *(const float4*)&As[k][tm<<2];
      float4 b4 = *(const float4*)&Bs[k][tn<<2];
      float aa[4]={a4.x,a4.y,a4.z,a4.w};
      float bb[4]={b4.x,b4.y,b4.z,b4.w};
      #pragma unroll
      for (int ii=0;ii<4;ii++)
        #pragma unroll
        for (int jj=0;jj<4;jj++)
          acc[ii][jj] = fmaf(aa[ii], bb[jj], acc[ii][jj]);
    }
  }
  #pragma unroll
  for (int ii=0;ii<4;ii++){
    float4 o; o.x=acc[ii][0]; o.y=acc[ii][1]; o.z=acc[ii][2]; o.w=acc[ii][3];
    *(float4*)(C + (size_t)(b0 + (tm<<2) + ii)*N + j0 + (tn<<2)) = o;
  }
}

// ---------------- LSTM cell elementwise (sums the two gate partials + bias) ----------------
__global__ __launch_bounds__(256) void cell_kernel(
    const float* __restrict__ g0, const float* __restrict__ g1, const float* __restrict__ bsum,
    float* __restrict__ h, float* __restrict__ c,
    const int* __restrict__ lengths, int t)
{
  int idx = blockIdx.x*256 + threadIdx.x;
  int b = idx >> 10, k = idx & (HID-1);
  if (lengths && t >= lengths[b]) return;   // encoder mask: keep old h,c
  size_t base = (size_t)b*NGATE + k;
  float gi = g0[base       ] + g1[base       ] + bsum[k       ];
  float gf = g0[base + 1024] + g1[base + 1024] + bsum[k + 1024];
  float gg = g0[base + 2048] + g1[base + 2048] + bsum[k + 2048];
  float go = g0[base + 3072] + g1[base + 3072] + bsum[k + 3072];
  float cc = c[idx];
  float cn = sigm(gf)*cc + sigm(gi)*tanhf(gg);
  float hn = sigm(go)*tanhf(cn);
  c[idx] = cn; h[idx] = hn;
}

// ---------------- decode step: gumbel+argmax, state update, fo write, next input ----------------
__global__ __launch_bounds__(256) void decide_kernel(
    const float* __restrict__ logits_raw, const float* __restrict__ b_fc, int t,
    const int* __restrict__ is_think_old, int* __restrict__ is_think_new,
    int* __restrict__ think_steps, int* __restrict__ out_steps,
    float* __restrict__ cur, float* __restrict__ out)
{
  int b = blockIdx.x, tid = threadIdx.x;
  // folded key = threefry2x32(key=(0,42), x=(0,t))  (fold_in is flag-independent)
  uint32_t fk0, fk1; tf2x32(0u, 42u, 0u, (uint32_t)t, fk0, fk1);

  float lg[4];
  float zb = -3.4e38f; int ib = 0;
  #pragma unroll
  for (int q=0;q<4;q++){
    int v = tid + (q<<8);                       // ascending v within thread
    uint32_t i = (uint32_t)(b*VOCAB + v);       // flat index into (256,1024) draw
    uint32_t bits = jax_bits(fk0, fk1, i);
    float f = __uint_as_float((bits>>9) | 0x3F800000u) - 1.0f;
    const float TINY = 1.17549435e-38f;
    float u = fmaxf(TINY, f + TINY);
    float g = -logf(-logf(u));
    float l = logits_raw[(size_t)b*VOCAB + v] + b_fc[v];
    lg[q] = l;
    float zz = l + g;
    if (zz > zb){ zb = zz; ib = v; }            // strict > keeps first index
  }

  __shared__ float smax[256]; __shared__ int sidxs[256];
  __shared__ int s_any, s_pred, s_outp, s_stepidx;
  smax[tid]=zb; sidxs[tid]=ib;
  if (tid==0) s_any = 0;
  __syncthreads();
  if (is_think_old[tid]) atomicOr(&s_any, 1);   // any() over PRE-update snapshot
  __syncthreads();
  for (int s=128;s>0;s>>=1){
    if (tid < s){
      float om=smax[tid+s]; int oi=sidxs[tid+s];
      if (om > smax[tid] || (om==smax[tid] && oi < sidxs[tid])){ smax[tid]=om; sidxs[tid]=oi; }
    }
    __syncthreads();
  }
  if (tid==0){
    int pred = sidxs[0]; s_pred = pred;
    int isth = is_think_old[b];
    int os = out_steps[b];
    int outp = (!isth && os < NOUT) ? 1 : 0;
    s_outp = outp;
    s_stepidx = os < (NOUT-1) ? os : (NOUT-1);
    int nts = think_steps[b] + (isth ? 1 : 0);
    out_steps[b] = os + outp;
    think_steps[b] = nts;
    int jf = (isth && ((pred==STOPCLS) || (nts >= MAXTHINK))) ? 1 : 0;
    is_think_new[b] = (isth && !jf) ? 1 : 0;
    if (t == TDEC-1) out[(size_t)BATCH*NOUT*(VOCAB-1) + b] = (float)nts;
  }
  __syncthreads();
  int any = s_any, pred = s_pred, outp = s_outp, si = s_stepidx;
  #pragma unroll
  for (int q=0;q<4;q++){
    int v = tid + (q<<8);
    float l = lg[q];
    // one_hot_out == y_hard (to 1ulp) in f32 forward; argmax position carries 1.0
    cur[(size_t)b*VOCAB + v] = any ? l : (v==pred ? 1.0f : 0.0f);
    if (outp && v < (VOCAB-1))
      out[((size_t)b*NOUT + si)*(VOCAB-1) + v] = l;
  }
}

// ---------------- host ----------------
extern "C" void kernel_launch(void* const* d_in, const int* in_sizes, int n_in,
                              void* d_out, int out_size, void* d_ws, size_t ws_size,
                              hipStream_t stream)
{
  const float* x    = (const float*)d_in[0];
  const float* W_ih = (const float*)d_in[1];
  const float* W_hh = (const float*)d_in[2];
  const float* b_ih = (const float*)d_in[3];
  const float* b_hh = (const float*)d_in[4];
  const float* W_fc = (const float*)d_in[5];
  const float* b_fc = (const float*)d_in[6];
  const int*   lengths = (const int*)d_in[7];
  float* out = (float*)d_out;

  float* ws   = (float*)d_ws;
  float* bsum = ws;                                   // 4096
  float* h    = bsum + NGATE;                         // 256*1024
  float* c    = h + (size_t)BATCH*HID;                // 256*1024
  float* g0   = c + (size_t)BATCH*HID;                // 256*4096
  float* g1   = g0 + (size_t)BATCH*NGATE;             // 256*4096
  float* cur  = g1 + (size_t)BATCH*NGATE;             // 256*1024
  float* logits = cur + (size_t)BATCH*HID;            // 256*1024
  int* ints = (int*)(logits + (size_t)BATCH*HID);
  int* is_think    = ints;        // [2][256] ping-pong
  int* think_steps = ints + 512;
  int* out_steps   = ints + 768;

  prep_kernel<<<1024, 256, 0, stream>>>(b_ih, b_hh, x, lengths, bsum, h, c, cur,
                                        is_think, think_steps, out_steps);

  dim3 gG(NGATE/GBN, BATCH/GBM, 2);   // (64,4,2) = 512 blocks
  dim3 gF(VOCAB/GBN, BATCH/GBM, 1);   // (16,4)

  for (int t = 0; t < TENC; ++t){
    gemm_nt<<<gG, 256, 0, stream>>>(x + (size_t)t*HID, TENC*HID, h, W_ih, W_hh, g0, g1, NGATE);
    cell_kernel<<<1024, 256, 0, stream>>>(g0, g1, bsum, h, c, lengths, t);
  }
  for (int t = 0; t < TDEC; ++t){
    gemm_nt<<<gG, 256, 0, stream>>>(cur, HID, h, W_ih, W_hh, g0, g1, NGATE);
    cell_kernel<<<1024, 256, 0, stream>>>(g0, g1, bsum, h, c, nullptr, 0);
    gemm_nt<<<gF, 256, 0, stream>>>(h, HID, nullptr, W_fc, nullptr, logits, nullptr, VOCAB);
    decide_kernel<<<BATCH, 256, 0, stream>>>(logits, b_fc, t,
                                             is_think + (t&1)*BATCH, is_think + ((t+1)&1)*BATCH,
                                             think_steps, out_steps, cur, out);
  }
}

// Round 4
// 17148.495 us; speedup vs baseline: 1.6561x; 1.6561x over previous
//
#include <hip/hip_runtime.h>
#include <stdint.h>

#define HID 1024
#define NGATE 4096
#define BATCH 256
#define TENC 128
#define VOCAB 1024
#define NOUT 125
#define TDEC (16 + NOUT)   // 141
#define MAXTHINK 16
#define STOPCLS 1023

typedef __attribute__((ext_vector_type(8))) short short8;
typedef __attribute__((ext_vector_type(4))) float f32x4;

// ---------------- threefry2x32 (exact JAX semantics, partitionable XOR-fold) ----------------
__device__ __forceinline__ uint32_t rotl32(uint32_t v, int r){ return (v<<r)|(v>>(32-r)); }

__device__ __forceinline__ void tf2x32(uint32_t k0, uint32_t k1, uint32_t x0, uint32_t x1,
                                       uint32_t& o0, uint32_t& o1)
{
  uint32_t k2 = k0 ^ k1 ^ 0x1BD11BDAu;
  x0 += k0; x1 += k1;
#define R4(a,b,cc,d) x0+=x1;x1=rotl32(x1,a);x1^=x0; x0+=x1;x1=rotl32(x1,b);x1^=x0; \
                     x0+=x1;x1=rotl32(x1,cc);x1^=x0; x0+=x1;x1=rotl32(x1,d);x1^=x0;
  R4(13,15,26,6)  x0+=k1; x1+=k2+1u;
  R4(17,29,16,24) x0+=k2; x1+=k0+2u;
  R4(13,15,26,6)  x0+=k0; x1+=k1+3u;
  R4(17,29,16,24) x0+=k1; x1+=k2+4u;
  R4(13,15,26,6)  x0+=k2; x1+=k0+5u;
#undef R4
  o0 = x0; o1 = x1;
}

__device__ __forceinline__ uint32_t jax_bits(uint32_t fk0, uint32_t fk1, uint32_t i)
{
  uint32_t o0, o1;
  tf2x32(fk0, fk1, 0u, i, o0, o1);   // 64-bit iota: hi=0, lo=i
  return o0 ^ o1;                     // XOR-fold (jax_threefry_partitionable)
}

__device__ __forceinline__ float sigm(float x){ return 0.5f + 0.5f*tanhf(0.5f*x); }

// bf16 round-to-nearest-even, manual (matches v_cvt semantics)
__device__ __forceinline__ ushort bf16rn(float v){
  uint32_t u = __float_as_uint(v);
  uint32_t r = (u + 0x7fffu + ((u>>16)&1u)) >> 16;
  return (ushort)r;
}
__device__ __forceinline__ float bf16tof(ushort s){ return __uint_as_float(((uint32_t)s)<<16); }

// ---------------- prep ----------------
__global__ __launch_bounds__(256) void prep_kernel(
    const float* __restrict__ b_ih, const float* __restrict__ b_hh,
    const float* __restrict__ x, const int* __restrict__ lengths,
    float* __restrict__ bsum, float* __restrict__ h, float* __restrict__ c,
    float* __restrict__ cur, int* __restrict__ is_think0,
    int* __restrict__ think_steps, int* __restrict__ out_steps)
{
  int idx = blockIdx.x*256 + threadIdx.x;           // 0 .. 262143
  if (idx < NGATE) bsum[idx] = b_ih[idx] + b_hh[idx];
  if (idx < BATCH){ is_think0[idx] = 1; think_steps[idx] = 0; out_steps[idx] = 0; }
  h[idx] = 0.f; c[idx] = 0.f;
  int b = idx >> 10, k = idx & (HID-1);
  int L = lengths[b];
  cur[idx] = x[((size_t)b*TENC + (size_t)(L-1))*HID + k];
}

// ---------------- split-bf16 MFMA GEMM: C[b][j] = sum_k A[b][k] * W[j][k] ----------------
// PL=3: 6-product split (f32-class accuracy). PL=1: plain bf16 (post-think only).
// Tile 64x64, BK=32 (one MFMA K). 4 waves in 2x2; each wave 32x32 via 2x2 16x16 frags.
template<int PL>
__global__ __launch_bounds__(256) void gemm_mfma(
    const float* __restrict__ A1, int lda1,
    const float* __restrict__ A2,
    const float* __restrict__ W1, const float* __restrict__ W2,
    float* __restrict__ C0, float* __restrict__ C1, int N)
{
  int z = blockIdx.z;
  const float* A = z ? A2 : A1;
  const float* W = z ? W2 : W1;
  int lda = z ? HID : lda1;
  float* C = z ? C1 : C0;

  __shared__ __align__(16) ushort As[PL][64][40];   // padded: row stride 80B (bank-friendly)
  __shared__ __align__(16) ushort Ws[PL][64][40];

  int tid  = threadIdx.x;
  int lane = tid & 63;
  int w    = tid >> 6;
  int j0 = blockIdx.x * 64;
  int b0 = blockIdx.y * 64;

  int srow = tid >> 2;          // 0..63 staging row
  int skp  = (tid & 3) * 8;     // 0,8,16,24 staging k-offset

  int mb = (w >> 1) * 32;
  int nb = (w & 1) * 32;
  int fr = lane & 15;           // frag row (A: m, B: n)
  int ko = (lane >> 4) * 8;     // frag k-octet offset

  f32x4 acc[2][2] = {};

  for (int k0 = 0; k0 < HID; k0 += 32){
    const float* ap = A + (size_t)(b0+srow)*lda + k0 + skp;
    const float* wp = W + (size_t)(j0+srow)*HID + k0 + skp;
    float av[8], wv[8];
    *(float4*)&av[0] = *(const float4*)ap;  *(float4*)&av[4] = *(const float4*)(ap+4);
    *(float4*)&wv[0] = *(const float4*)wp;  *(float4*)&wv[4] = *(const float4*)(wp+4);
    __syncthreads();                       // previous iter's frag reads done
    #pragma unroll
    for (int e=0;e<8;e++){
      float va = av[e], vw = wv[e];
      #pragma unroll
      for (int p=0;p<PL;p++){
        ushort pa = bf16rn(va); va -= bf16tof(pa); As[p][srow][skp+e] = pa;
        ushort pw = bf16rn(vw); vw -= bf16tof(pw); Ws[p][srow][skp+e] = pw;
      }
    }
    __syncthreads();
    short8 a[PL][2], b[PL][2];
    #pragma unroll
    for (int p=0;p<PL;p++)
      #pragma unroll
      for (int f=0;f<2;f++){
        a[p][f] = *(const short8*)&As[p][mb + f*16 + fr][ko];
        b[p][f] = *(const short8*)&Ws[p][nb + f*16 + fr][ko];
      }
    #pragma unroll
    for (int f=0;f<2;f++)
      #pragma unroll
      for (int g=0;g<2;g++){
        if constexpr (PL==3){
          // smallest-magnitude first; terms >= 2^-18 kept -> ~2^-27 rel err
          acc[f][g] = __builtin_amdgcn_mfma_f32_16x16x32_bf16(a[2][f], b[0][g], acc[f][g], 0,0,0);
          acc[f][g] = __builtin_amdgcn_mfma_f32_16x16x32_bf16(a[1][f], b[1][g], acc[f][g], 0,0,0);
          acc[f][g] = __builtin_amdgcn_mfma_f32_16x16x32_bf16(a[0][f], b[2][g], acc[f][g], 0,0,0);
          acc[f][g] = __builtin_amdgcn_mfma_f32_16x16x32_bf16(a[1][f], b[0][g], acc[f][g], 0,0,0);
          acc[f][g] = __builtin_amdgcn_mfma_f32_16x16x32_bf16(a[0][f], b[1][g], acc[f][g], 0,0,0);
          acc[f][g] = __builtin_amdgcn_mfma_f32_16x16x32_bf16(a[0][f], b[0][g], acc[f][g], 0,0,0);
        } else {
          acc[f][g] = __builtin_amdgcn_mfma_f32_16x16x32_bf16(a[0][f], b[0][g], acc[f][g], 0,0,0);
        }
      }
  }
  // C/D layout (m89-verified): col = lane&15, row = (lane>>4)*4 + reg
  int crow = (lane >> 4) * 4;
  int ccol = lane & 15;
  #pragma unroll
  for (int f=0;f<2;f++)
    #pragma unroll
    for (int g=0;g<2;g++)
      #pragma unroll
      for (int r=0;r<4;r++)
        C[(size_t)(b0 + mb + f*16 + crow + r)*N + (j0 + nb + g*16 + ccol)] = acc[f][g][r];
}

// ---------------- LSTM cell elementwise (dense: g0 + g1 + bias) ----------------
__global__ __launch_bounds__(256) void cell_kernel(
    const float* __restrict__ g0, const float* __restrict__ g1, const float* __restrict__ bsum,
    float* __restrict__ h, float* __restrict__ c,
    const int* __restrict__ lengths, int t)
{
  int idx = blockIdx.x*256 + threadIdx.x;
  int b = idx >> 10, k = idx & (HID-1);
  if (lengths && t >= lengths[b]) return;   // encoder mask: keep old h,c
  size_t base = (size_t)b*NGATE + k;
  float gi = g0[base       ] + g1[base       ] + bsum[k       ];
  float gf = g0[base + 1024] + g1[base + 1024] + bsum[k + 1024];
  float gg = g0[base + 2048] + g1[base + 2048] + bsum[k + 2048];
  float go = g0[base + 3072] + g1[base + 3072] + bsum[k + 3072];
  float cc = c[idx];
  float cn = sigm(gf)*cc + sigm(gi)*tanhf(gg);
  float hn = sigm(go)*tanhf(cn);
  c[idx] = cn; h[idx] = hn;
}

// ---------------- out-phase cell: x-side is one-hot -> W_ih column gather ----------------
__global__ __launch_bounds__(256) void cell_out_kernel(
    const float* __restrict__ g1, const float* __restrict__ bsum,
    const float* __restrict__ W_ih, const int* __restrict__ pred,
    float* __restrict__ h, float* __restrict__ c)
{
  int idx = blockIdx.x*256 + threadIdx.x;
  int b = idx >> 10, k = idx & (HID-1);
  int p = pred[b];
  size_t base = (size_t)b*NGATE + k;
  float gi = g1[base       ] + W_ih[(size_t)(k       )*HID + p] + bsum[k       ];
  float gf = g1[base + 1024] + W_ih[(size_t)(k + 1024)*HID + p] + bsum[k + 1024];
  float gg = g1[base + 2048] + W_ih[(size_t)(k + 2048)*HID + p] + bsum[k + 2048];
  float go = g1[base + 3072] + W_ih[(size_t)(k + 3072)*HID + p] + bsum[k + 3072];
  float cc = c[idx];
  float cn = sigm(gf)*cc + sigm(gi)*tanhf(gg);
  float hn = sigm(go)*tanhf(cn);
  c[idx] = cn; h[idx] = hn;
}

// ---------------- decode step: gumbel+argmax, state update, fo write, next input ----------------
__global__ __launch_bounds__(256) void decide_kernel(
    const float* __restrict__ logits_raw, const float* __restrict__ b_fc, int t,
    const int* __restrict__ is_think_old, int* __restrict__ is_think_new,
    int* __restrict__ think_steps, int* __restrict__ out_steps,
    int* __restrict__ pred_out,
    float* __restrict__ cur, float* __restrict__ out)
{
  int b = blockIdx.x, tid = threadIdx.x;
  uint32_t fk0, fk1; tf2x32(0u, 42u, 0u, (uint32_t)t, fk0, fk1);

  float lg[4];
  float zb = -3.4e38f; int ib = 0;
  #pragma unroll
  for (int q=0;q<4;q++){
    int v = tid + (q<<8);
    uint32_t i = (uint32_t)(b*VOCAB + v);
    uint32_t bits = jax_bits(fk0, fk1, i);
    float f = __uint_as_float((bits>>9) | 0x3F800000u) - 1.0f;
    const float TINY = 1.17549435e-38f;
    float u = fmaxf(TINY, f + TINY);
    float g = -logf(-logf(u));
    float l = logits_raw[(size_t)b*VOCAB + v] + b_fc[v];
    lg[q] = l;
    float zz = l + g;
    if (zz > zb){ zb = zz; ib = v; }
  }

  __shared__ float smax[256]; __shared__ int sidxs[256];
  __shared__ int s_any, s_pred, s_outp, s_stepidx;
  smax[tid]=zb; sidxs[tid]=ib;
  if (tid==0) s_any = 0;
  __syncthreads();
  if (is_think_old[tid]) atomicOr(&s_any, 1);   // any() over PRE-update snapshot
  __syncthreads();
  for (int s=128;s>0;s>>=1){
    if (tid < s){
      float om=smax[tid+s]; int oi=sidxs[tid+s];
      if (om > smax[tid] || (om==smax[tid] && oi < sidxs[tid])){ smax[tid]=om; sidxs[tid]=oi; }
    }
    __syncthreads();
  }
  if (tid==0){
    int pred = sidxs[0]; s_pred = pred;
    pred_out[b] = pred;
    int isth = is_think_old[b];
    int os = out_steps[b];
    int outp = (!isth && os < NOUT) ? 1 : 0;
    s_outp = outp;
    s_stepidx = os < (NOUT-1) ? os : (NOUT-1);
    int nts = think_steps[b] + (isth ? 1 : 0);
    out_steps[b] = os + outp;
    think_steps[b] = nts;
    int jf = (isth && ((pred==STOPCLS) || (nts >= MAXTHINK))) ? 1 : 0;
    is_think_new[b] = (isth && !jf) ? 1 : 0;
    if (t == TDEC-1) out[(size_t)BATCH*NOUT*(VOCAB-1) + b] = (float)nts;
  }
  __syncthreads();
  int any = s_any, pred = s_pred, outp = s_outp, si = s_stepidx;
  #pragma unroll
  for (int q=0;q<4;q++){
    int v = tid + (q<<8);
    float l = lg[q];
    cur[(size_t)b*VOCAB + v] = any ? l : (v==pred ? 1.0f : 0.0f);
    if (outp && v < (VOCAB-1))
      out[((size_t)b*NOUT + si)*(VOCAB-1) + v] = l;
  }
}

// ---------------- host ----------------
extern "C" void kernel_launch(void* const* d_in, const int* in_sizes, int n_in,
                              void* d_out, int out_size, void* d_ws, size_t ws_size,
                              hipStream_t stream)
{
  const float* x    = (const float*)d_in[0];
  const float* W_ih = (const float*)d_in[1];
  const float* W_hh = (const float*)d_in[2];
  const float* b_ih = (const float*)d_in[3];
  const float* b_hh = (const float*)d_in[4];
  const float* W_fc = (const float*)d_in[5];
  const float* b_fc = (const float*)d_in[6];
  const int*   lengths = (const int*)d_in[7];
  float* out = (float*)d_out;

  float* ws   = (float*)d_ws;
  float* bsum = ws;                                   // 4096
  float* h    = bsum + NGATE;                         // 256*1024
  float* c    = h + (size_t)BATCH*HID;                // 256*1024
  float* g0   = c + (size_t)BATCH*HID;                // 256*4096
  float* g1   = g0 + (size_t)BATCH*NGATE;             // 256*4096
  float* cur  = g1 + (size_t)BATCH*NGATE;             // 256*1024
  float* logits = cur + (size_t)BATCH*HID;            // 256*1024
  int* ints = (int*)(logits + (size_t)BATCH*HID);
  int* is_think    = ints;        // [2][256] ping-pong
  int* think_steps = ints + 512;
  int* out_steps   = ints + 768;
  int* pred        = ints + 1024;

  prep_kernel<<<1024, 256, 0, stream>>>(b_ih, b_hh, x, lengths, bsum, h, c, cur,
                                        is_think, think_steps, out_steps);

  dim3 gG(NGATE/64, BATCH/64, 2);    // (64,4,2) = 512 blocks, both matmuls
  dim3 gG1(NGATE/64, BATCH/64, 1);   // h*W_hh only
  dim3 gF(VOCAB/64, BATCH/64, 1);    // (16,4)

  for (int t = 0; t < TENC; ++t){
    gemm_mfma<3><<<gG, 256, 0, stream>>>(x + (size_t)t*HID, TENC*HID, h, W_ih, W_hh, g0, g1, NGATE);
    cell_kernel<<<1024, 256, 0, stream>>>(g0, g1, bsum, h, c, lengths, t);
  }
  for (int t = 0; t < TDEC; ++t){
    if (t < MAXTHINK){
      // trajectory-critical: f32-class split path
      gemm_mfma<3><<<gG, 256, 0, stream>>>(cur, HID, h, W_ih, W_hh, g0, g1, NGATE);
      cell_kernel<<<1024, 256, 0, stream>>>(g0, g1, bsum, h, c, nullptr, 0);
      gemm_mfma<3><<<gF, 256, 0, stream>>>(h, HID, nullptr, W_fc, nullptr, logits, nullptr, VOCAB);
    } else {
      // t>=16: is_think statically all-false -> cur is one-hot; only fo (loose) depends on this
      gemm_mfma<1><<<gG1, 256, 0, stream>>>(h, HID, nullptr, W_hh, nullptr, g1, nullptr, NGATE);
      cell_out_kernel<<<1024, 256, 0, stream>>>(g1, bsum, W_ih, pred, h, c);
      gemm_mfma<1><<<gF, 256, 0, stream>>>(h, HID, nullptr, W_fc, nullptr, logits, nullptr, VOCAB);
    }
    decide_kernel<<<BATCH, 256, 0, stream>>>(logits, b_fc, t,
                                             is_think + (t&1)*BATCH, is_think + ((t+1)&1)*BATCH,
                                             think_steps, out_steps, pred, cur, out);
  }
}